// Round 3
// baseline (314.788 us; speedup 1.0000x reference)
//
#include <hip/hip_runtime.h>

#define BATCH 4
#define SEQ   2048
#define EMB   128
#define NH    16
#define DK    8

#define SPLITS 4
#define KCHUNK (SEQ / SPLITS)   // 512 keys per split group

// log2(e) / sqrt(8): fold softmax temperature into exp2 (pre-multiplied into q)
#define QSCALE 0.510069726f

// ---------------------------------------------------------------------------
// Kernel 1: quantum features. f[bh][s][d] = prod_{i<=d} cos(x[b,s,h*8+i]+th[i])
// One thread per (bh, s) row. |f| <= 1 always.
// ---------------------------------------------------------------------------
__global__ void feat_kernel(const float* __restrict__ x,
                            const float* __restrict__ theta,
                            float* __restrict__ f /* [64][2048][8] */) {
  const int gid = blockIdx.x * 256 + threadIdx.x;  // bh*2048 + s
  const int bh = gid >> 11;
  const int s  = gid & (SEQ - 1);
  const int b  = bh >> 4;
  const int h  = bh & 15;

  const float4* xp = (const float4*)(x + ((size_t)b * SEQ + s) * EMB + h * DK);
  const float4 xa = xp[0];
  const float4 xb = xp[1];

  const float f0 = __cosf(xa.x + theta[0]);
  const float f1 = f0 * __cosf(xa.y + theta[1]);
  const float f2 = f1 * __cosf(xa.z + theta[2]);
  const float f3 = f2 * __cosf(xa.w + theta[3]);
  const float f4 = f3 * __cosf(xb.x + theta[4]);
  const float f5 = f4 * __cosf(xb.y + theta[5]);
  const float f6 = f5 * __cosf(xb.z + theta[6]);
  const float f7 = f6 * __cosf(xb.w + theta[7]);

  float4* fp = (float4*)(f + (size_t)gid * DK);
  fp[0] = make_float4(f0, f1, f2, f3);
  fp[1] = make_float4(f4, f5, f6, f7);
}

// ---------------------------------------------------------------------------
// Kernel 2: self-attention (q == k == v), key-split x4 inside the block.
// Block = 1024 threads = 256 rows x 4 key-splits; grid = 64 bh x 8 row-chunks
// = 512 blocks -> 2 blocks/CU -> 32 waves/CU = 8 waves/SIMD.
// Keys streamed via wave-uniform (scalarized) loads from the L2-hot feature
// buffer. exp2 via raw v_exp_f32 (__builtin_amdgcn_exp2f): |d| <= 4.1, exact.
// Partials combined through LDS (9-float row stride -> conflict-free).
// ---------------------------------------------------------------------------
__launch_bounds__(1024, 8)
__global__ void attn_kernel(const float* __restrict__ f,
                            float* __restrict__ att /* [B*S][128] = d_out */) {
  __shared__ float part[SPLITS][256][9];   // 36 KB

  const int tid   = threadIdx.x;
  const int rloc  = tid & 255;
  const int split = tid >> 8;
  const int bh    = blockIdx.x >> 3;
  const int chunk = blockIdx.x & 7;
  const int row   = chunk * 256 + rloc;

  const float4* __restrict__ kf = (const float4*)(f + (size_t)bh * SEQ * DK);

  // own query row, pre-scaled
  const float4 qa = kf[2 * row];
  const float4 qb = kf[2 * row + 1];
  const float q0 = qa.x * QSCALE, q1 = qa.y * QSCALE;
  const float q2 = qa.z * QSCALE, q3 = qa.w * QSCALE;
  const float q4 = qb.x * QSCALE, q5 = qb.y * QSCALE;
  const float q6 = qb.z * QSCALE, q7 = qb.w * QSCALE;

  float a0 = 0.f, a1 = 0.f, a2 = 0.f, a3 = 0.f;
  float a4 = 0.f, a5 = 0.f, a6 = 0.f, a7 = 0.f;
  float den = 0.f;

  const int j0 = split * KCHUNK;
#pragma unroll 4
  for (int j = j0; j < j0 + KCHUNK; ++j) {
    const float4 ka = kf[2 * j];      // wave-uniform address -> s_load
    const float4 kb = kf[2 * j + 1];
    float d = q0 * ka.x;
    d = fmaf(q1, ka.y, d);
    d = fmaf(q2, ka.z, d);
    d = fmaf(q3, ka.w, d);
    d = fmaf(q4, kb.x, d);
    d = fmaf(q5, kb.y, d);
    d = fmaf(q6, kb.z, d);
    d = fmaf(q7, kb.w, d);
    const float w = __builtin_amdgcn_exp2f(d);  // raw v_exp_f32
    den += w;
    a0 = fmaf(w, ka.x, a0);
    a1 = fmaf(w, ka.y, a1);
    a2 = fmaf(w, ka.z, a2);
    a3 = fmaf(w, ka.w, a3);
    a4 = fmaf(w, kb.x, a4);
    a5 = fmaf(w, kb.y, a5);
    a6 = fmaf(w, kb.z, a6);
    a7 = fmaf(w, kb.w, a7);
  }

  // ---- combine the 4 key-split partials through LDS ----
  if (split != 0) {
    float* p = &part[split][rloc][0];
    p[0] = a0; p[1] = a1; p[2] = a2; p[3] = a3;
    p[4] = a4; p[5] = a5; p[6] = a6; p[7] = a7;
    p[8] = den;
  }
  __syncthreads();

  if (split == 0) {
#pragma unroll
    for (int s = 1; s < SPLITS; ++s) {
      const float* p = &part[s][rloc][0];
      a0 += p[0]; a1 += p[1]; a2 += p[2]; a3 += p[3];
      a4 += p[4]; a5 += p[5]; a6 += p[6]; a7 += p[7];
      den += p[8];
    }
    const int b = bh >> 4;
    const int h = bh & 15;
    const float inv = 1.0f / den;
    float* op = att + ((size_t)b * SEQ + row) * EMB + h * DK;
    ((float4*)op)[0] = make_float4(a0 * inv, a1 * inv, a2 * inv, a3 * inv);
    ((float4*)op)[1] = make_float4(a4 * inv, a5 * inv, a6 * inv, a7 * inv);
  }
}

// ---------------------------------------------------------------------------
// Kernel 3: output projection, IN-PLACE on d_out.
// out[r,c] = sum_e A[r,e] * W[c,e]; A == out buffer ([16384,128]).
// Safe in-place: each block owns 64 rows x ALL 128 cols, and writes only
// after the k-loop has staged every A element of those rows into LDS.
// ---------------------------------------------------------------------------
#define PBM 64
#define PBK 32
#define APITCH 68   // 68*4 = 272 bytes, 16B-aligned rows
#define WPITCH 132  // 132*4 = 528 bytes, 16B-aligned rows

__launch_bounds__(256, 2)
__global__ void proj_kernel(float* __restrict__ AO /* A and out, in-place */,
                            const float* __restrict__ W) {
  __shared__ float As[PBK][APITCH];
  __shared__ float Ws[PBK][WPITCH];

  const int tid = threadIdx.x;
  const int tx = tid & 15;   // 16 col groups of 8
  const int ty = tid >> 4;   // 16 row groups of 4
  const int rowbase = blockIdx.x * PBM;

  float acc[4][8] = {{0.f}};

  for (int e0 = 0; e0 < EMB; e0 += PBK) {
    // stage A^T tile: As[e][m] = A[rowbase+m][e0+e]   (64 rows x 32 k)
    for (int it = 0; it < 2; ++it) {
      const int idx = it * 256 + tid;        // 512 float4 loads
      const int m = idx >> 3;
      const int e4 = idx & 7;
      const float4 v = *(const float4*)(AO + (size_t)(rowbase + m) * EMB + e0 + e4 * 4);
      As[e4 * 4 + 0][m] = v.x;
      As[e4 * 4 + 1][m] = v.y;
      As[e4 * 4 + 2][m] = v.z;
      As[e4 * 4 + 3][m] = v.w;
    }
    // stage W^T tile: Ws[e][n] = W[n][e0+e]   (128 cols x 32 k)
    for (int it = 0; it < 4; ++it) {
      const int idx = it * 256 + tid;        // 1024 float4 loads
      const int n = idx >> 3;
      const int e4 = idx & 7;
      const float4 v = *(const float4*)(W + (size_t)n * EMB + e0 + e4 * 4);
      Ws[e4 * 4 + 0][n] = v.x;
      Ws[e4 * 4 + 1][n] = v.y;
      Ws[e4 * 4 + 2][n] = v.z;
      Ws[e4 * 4 + 3][n] = v.w;
    }
    __syncthreads();

#pragma unroll
    for (int e = 0; e < PBK; ++e) {
      const float4 av = *(const float4*)&As[e][ty * 4];
      const float4 w0 = *(const float4*)&Ws[e][tx * 8];
      const float4 w1 = *(const float4*)&Ws[e][tx * 8 + 4];
      const float a[4] = {av.x, av.y, av.z, av.w};
      const float w[8] = {w0.x, w0.y, w0.z, w0.w, w1.x, w1.y, w1.z, w1.w};
#pragma unroll
      for (int i = 0; i < 4; ++i)
#pragma unroll
        for (int jj = 0; jj < 8; ++jj) acc[i][jj] = fmaf(a[i], w[jj], acc[i][jj]);
    }
    __syncthreads();
  }

#pragma unroll
  for (int i = 0; i < 4; ++i) {
    float* op = AO + (size_t)(rowbase + ty * 4 + i) * EMB + tx * 8;
    ((float4*)op)[0] = make_float4(acc[i][0], acc[i][1], acc[i][2], acc[i][3]);
    ((float4*)op)[1] = make_float4(acc[i][4], acc[i][5], acc[i][6], acc[i][7]);
  }
}

// ---------------------------------------------------------------------------
extern "C" void kernel_launch(void* const* d_in, const int* in_sizes, int n_in,
                              void* d_out, int out_size, void* d_ws, size_t ws_size,
                              hipStream_t stream) {
  const float* x     = (const float*)d_in[0];  // [4,2048,128]
  const float* theta = (const float*)d_in[1];  // [8]
  const float* w_out = (const float*)d_in[2];  // [128,128]
  float* out = (float*)d_out;                  // [4,2048,128]; also att scratch
  float* f   = (float*)d_ws;                   // [64,2048,8] features (4 MB)

  // features: 131072 rows / 256 = 512 blocks
  feat_kernel<<<dim3(512), dim3(256), 0, stream>>>(x, theta, f);

  // attention: 64 bh x 8 row-chunks = 512 blocks of 1024 (256 rows x 4 splits)
  attn_kernel<<<dim3(512), dim3(1024), 0, stream>>>(f, out);

  // projection in-place on d_out: 16384/64 = 256 blocks
  proj_kernel<<<dim3((BATCH * SEQ) / PBM), dim3(256), 0, stream>>>(out, w_out);
}

// Round 4
// 222.693 us; speedup vs baseline: 1.4135x; 1.4135x over previous
//
#include <hip/hip_runtime.h>

#define BATCH 4
#define SEQ   2048
#define EMB   128
#define NH    16
#define DK    8

#define SPLITS 4
#define KCHUNK (SEQ / SPLITS)   // 512 keys per split group

// log2(e) / sqrt(8): fold softmax temperature into exp2 (pre-multiplied into q)
#define QSCALE 0.510069726f

// ---------------------------------------------------------------------------
// Kernel 1: quantum features. f[bh][s][d] = prod_{i<=d} cos(x[b,s,h*8+i]+th[i])
// One thread per (bh, s) row. |f| <= 1 always.
// ---------------------------------------------------------------------------
__global__ void feat_kernel(const float* __restrict__ x,
                            const float* __restrict__ theta,
                            float* __restrict__ f /* [64][2048][8] */) {
  const int gid = blockIdx.x * 256 + threadIdx.x;  // bh*2048 + s
  const int bh = gid >> 11;
  const int s  = gid & (SEQ - 1);
  const int b  = bh >> 4;
  const int h  = bh & 15;

  const float4* xp = (const float4*)(x + ((size_t)b * SEQ + s) * EMB + h * DK);
  const float4 xa = xp[0];
  const float4 xb = xp[1];

  const float f0 = __cosf(xa.x + theta[0]);
  const float f1 = f0 * __cosf(xa.y + theta[1]);
  const float f2 = f1 * __cosf(xa.z + theta[2]);
  const float f3 = f2 * __cosf(xa.w + theta[3]);
  const float f4 = f3 * __cosf(xb.x + theta[4]);
  const float f5 = f4 * __cosf(xb.y + theta[5]);
  const float f6 = f5 * __cosf(xb.z + theta[6]);
  const float f7 = f6 * __cosf(xb.w + theta[7]);

  float4* fp = (float4*)(f + (size_t)gid * DK);
  fp[0] = make_float4(f0, f1, f2, f3);
  fp[1] = make_float4(f4, f5, f6, f7);
}

// ---------------------------------------------------------------------------
// Kernel 2: self-attention (q == k == v), key-split x4 inside the block.
// Block = 1024 threads = 256 rows x 4 key-splits; grid = 512 -> 2 blocks/CU
// -> 32 waves/CU = 8 waves/SIMD.
// CRITICAL: split must be wave-uniform *provably* so the key loads scalarize
// to s_load (keeps the VMEM pipe empty). readfirstlane makes it an SGPR.
// exp2 via raw v_exp_f32: |d| <= 8/sqrt(8)*log2e ~ 4.1, exact there.
// ---------------------------------------------------------------------------
__launch_bounds__(1024, 8)
__global__ void attn_kernel(const float* __restrict__ f,
                            float* __restrict__ att /* [B*S][128] = d_out */) {
  __shared__ float part[SPLITS][256][9];   // 36 KB

  const int tid   = threadIdx.x;
  const int rloc  = tid & 255;
  // tid>>8 is constant across a 64-lane wave; make that visible -> SGPR
  const int split = __builtin_amdgcn_readfirstlane(tid >> 8);
  const int bh    = blockIdx.x >> 3;
  const int chunk = blockIdx.x & 7;
  const int row   = chunk * 256 + rloc;

  const float4* __restrict__ kf = (const float4*)(f + (size_t)bh * SEQ * DK);

  // own query row, pre-scaled
  const float4 qa = kf[2 * row];
  const float4 qb = kf[2 * row + 1];
  const float q0 = qa.x * QSCALE, q1 = qa.y * QSCALE;
  const float q2 = qa.z * QSCALE, q3 = qa.w * QSCALE;
  const float q4 = qb.x * QSCALE, q5 = qb.y * QSCALE;
  const float q6 = qb.z * QSCALE, q7 = qb.w * QSCALE;

  float a0 = 0.f, a1 = 0.f, a2 = 0.f, a3 = 0.f;
  float a4 = 0.f, a5 = 0.f, a6 = 0.f, a7 = 0.f;
  float den = 0.f;

  const int j0 = split * KCHUNK;
#pragma unroll 4
  for (int j = j0; j < j0 + KCHUNK; ++j) {
    const float4 ka = kf[2 * j];      // scalar (uniform) address -> s_load
    const float4 kb = kf[2 * j + 1];
    float d = q0 * ka.x;
    d = fmaf(q1, ka.y, d);
    d = fmaf(q2, ka.z, d);
    d = fmaf(q3, ka.w, d);
    d = fmaf(q4, kb.x, d);
    d = fmaf(q5, kb.y, d);
    d = fmaf(q6, kb.z, d);
    d = fmaf(q7, kb.w, d);
    const float w = __builtin_amdgcn_exp2f(d);  // raw v_exp_f32
    den += w;
    a0 = fmaf(w, ka.x, a0);
    a1 = fmaf(w, ka.y, a1);
    a2 = fmaf(w, ka.z, a2);
    a3 = fmaf(w, ka.w, a3);
    a4 = fmaf(w, kb.x, a4);
    a5 = fmaf(w, kb.y, a5);
    a6 = fmaf(w, kb.z, a6);
    a7 = fmaf(w, kb.w, a7);
  }

  // ---- combine the 4 key-split partials through LDS ----
  if (split != 0) {
    float* p = &part[split][rloc][0];
    p[0] = a0; p[1] = a1; p[2] = a2; p[3] = a3;
    p[4] = a4; p[5] = a5; p[6] = a6; p[7] = a7;
    p[8] = den;
  }
  __syncthreads();

  if (split == 0) {
#pragma unroll
    for (int s = 1; s < SPLITS; ++s) {
      const float* p = &part[s][rloc][0];
      a0 += p[0]; a1 += p[1]; a2 += p[2]; a3 += p[3];
      a4 += p[4]; a5 += p[5]; a6 += p[6]; a7 += p[7];
      den += p[8];
    }
    const int b = bh >> 4;
    const int h = bh & 15;
    const float inv = 1.0f / den;
    float* op = att + ((size_t)b * SEQ + row) * EMB + h * DK;
    ((float4*)op)[0] = make_float4(a0 * inv, a1 * inv, a2 * inv, a3 * inv);
    ((float4*)op)[1] = make_float4(a4 * inv, a5 * inv, a6 * inv, a7 * inv);
  }
}

// ---------------------------------------------------------------------------
// Kernel 3: output projection, IN-PLACE on d_out (in-place forces full-row
// blocks: each block owns 64 rows x ALL 128 cols).
// Single-stage: A-tile (64x128) + full W (128x128) staged row-major into LDS
// with pure float4 copies (no transpose), ONE barrier, then a full-K loop.
// Col mapping c = tx + 16*jj: W-row LDS reads are 2-way-conflict (free).
// LDS = 64*132*4 + 128*132*4 = 101376 B -> 1 block/CU, grid 256 = 1/CU.
// ---------------------------------------------------------------------------
#define PPITCH 132  // 132*4 = 528 B row pitch, 16B-aligned, breaks pow2 stride

__launch_bounds__(256, 1)
__global__ void proj_kernel(float* __restrict__ AO /* A and out, in-place */,
                            const float* __restrict__ W) {
  __shared__ float As[64][PPITCH];
  __shared__ float Ws[EMB][PPITCH];

  const int tid = threadIdx.x;
  const int tx = tid & 15;   // col group: cols tx + 16*jj, jj=0..7
  const int ty = tid >> 4;   // row group: rows ty*4 + i, i=0..3
  const int rowbase = blockIdx.x * 64;

  // stage A tile: 64 rows x 128 -> 2048 float4, 8 per thread
#pragma unroll
  for (int it = 0; it < 8; ++it) {
    const int idx = it * 256 + tid;
    const int m  = idx >> 5;          // 0..63
    const int e4 = idx & 31;          // 0..31
    const float4 v = *(const float4*)(AO + (size_t)(rowbase + m) * EMB + e4 * 4);
    *(float4*)&As[m][e4 * 4] = v;
  }
  // stage full W: 128 rows x 128 -> 4096 float4, 16 per thread
#pragma unroll
  for (int it = 0; it < 16; ++it) {
    const int idx = it * 256 + tid;
    const int n  = idx >> 5;          // 0..127
    const int e4 = idx & 31;
    const float4 v = *(const float4*)(W + (size_t)n * EMB + e4 * 4);
    *(float4*)&Ws[n][e4 * 4] = v;
  }
  __syncthreads();

  float acc[4][8] = {{0.f}};

#pragma unroll 2
  for (int e = 0; e < EMB; e += 4) {
    float4 av[4], wv[8];
#pragma unroll
    for (int i = 0; i < 4; ++i) av[i] = *(const float4*)&As[ty * 4 + i][e];
#pragma unroll
    for (int jj = 0; jj < 8; ++jj) wv[jj] = *(const float4*)&Ws[tx + 16 * jj][e];
#pragma unroll
    for (int i = 0; i < 4; ++i)
#pragma unroll
      for (int jj = 0; jj < 8; ++jj) {
        acc[i][jj] = fmaf(av[i].x, wv[jj].x, acc[i][jj]);
        acc[i][jj] = fmaf(av[i].y, wv[jj].y, acc[i][jj]);
        acc[i][jj] = fmaf(av[i].z, wv[jj].z, acc[i][jj]);
        acc[i][jj] = fmaf(av[i].w, wv[jj].w, acc[i][jj]);
      }
  }

#pragma unroll
  for (int i = 0; i < 4; ++i) {
    float* op = AO + (size_t)(rowbase + ty * 4 + i) * EMB;
#pragma unroll
    for (int jj = 0; jj < 8; ++jj) op[tx + 16 * jj] = acc[i][jj];
  }
}

// ---------------------------------------------------------------------------
extern "C" void kernel_launch(void* const* d_in, const int* in_sizes, int n_in,
                              void* d_out, int out_size, void* d_ws, size_t ws_size,
                              hipStream_t stream) {
  const float* x     = (const float*)d_in[0];  // [4,2048,128]
  const float* theta = (const float*)d_in[1];  // [8]
  const float* w_out = (const float*)d_in[2];  // [128,128]
  float* out = (float*)d_out;                  // [4,2048,128]; also att scratch
  float* f   = (float*)d_ws;                   // [64,2048,8] features (4 MB)

  // features: 131072 rows / 256 = 512 blocks
  feat_kernel<<<dim3(512), dim3(256), 0, stream>>>(x, theta, f);

  // attention: 64 bh x 8 row-chunks = 512 blocks of 1024 (256 rows x 4 splits)
  attn_kernel<<<dim3(512), dim3(1024), 0, stream>>>(f, out);

  // projection in-place on d_out: 16384/64 = 256 blocks
  proj_kernel<<<dim3((BATCH * SEQ) / 64), dim3(256), 0, stream>>>(out, w_out);
}